// Round 1
// baseline (348.353 us; speedup 1.0000x reference)
//
#include <hip/hip_runtime.h>
#include <hip/hip_bf16.h>

typedef __attribute__((ext_vector_type(8))) short short8;
typedef __attribute__((ext_vector_type(4))) short short4v;
typedef __attribute__((ext_vector_type(4))) float f32x4;

static __device__ __forceinline__ short f2bf(float f) {
    __hip_bfloat16 h = __float2bfloat16(f);
    return __builtin_bit_cast(short, h);
}

// ---------------- fp32 -> bf16 convert ----------------
__global__ __launch_bounds__(256) void convert_f32_bf16(
        const float* __restrict__ in, short* __restrict__ out, int n4) {
    int i = blockIdx.x * blockDim.x + threadIdx.x;
    int stride = gridDim.x * blockDim.x;
    for (; i < n4; i += stride) {
        f32x4 v = reinterpret_cast<const f32x4*>(in)[i];
        short4v o;
        o.x = f2bf(v.x); o.y = f2bf(v.y); o.z = f2bf(v.z); o.w = f2bf(v.w);
        reinterpret_cast<short4v*>(out)[i] = o;
    }
}

// ---------------- NT GEMM: C[M,N] = A[M,K] @ W[N,K]^T + bias ----------------
// M=4096, N=1024, K=1024. 128x128 tile, 4 waves (2x2), BK=64, 16x16x32 bf16 MFMA.
// MODE 0: out = bf16 q head-split [B,H,S,64], value scaled by 0.125
// MODE 1: out = bf16 k head-split [B,H,S,64]
// MODE 2: out = bf16 v transposed  [B,H,64,S]
// MODE 3: out = fp32 [M,N]
template<int MODE>
__global__ __launch_bounds__(256) void gemm_nt(
        const short* __restrict__ A, const short* __restrict__ W,
        const float* __restrict__ bias, void* __restrict__ out0) {
    constexpr int K = 1024;
    __shared__ __align__(16) short aS[128 * 72];
    __shared__ __align__(16) short bS[128 * 72];
    const int tid = threadIdx.x;
    const int lane = tid & 63;
    const int w = tid >> 6;
    const int wr = w >> 1, wc = w & 1;
    const int bn = blockIdx.x & 7;   // N/128 = 8
    const int bm = blockIdx.x >> 3;  // M/128 = 32
    const int l15 = lane & 15, lq = lane >> 4;

    f32x4 acc[4][4] = {};

    for (int k0 = 0; k0 < K; k0 += 64) {
#pragma unroll
        for (int j = 0; j < 4; ++j) {
            int c = tid + 256 * j;
            int r = c >> 3, kc = (c & 7) << 3;
            *reinterpret_cast<short8*>(&aS[r * 72 + kc]) =
                *reinterpret_cast<const short8*>(&A[(size_t)(bm * 128 + r) * K + k0 + kc]);
            *reinterpret_cast<short8*>(&bS[r * 72 + kc]) =
                *reinterpret_cast<const short8*>(&W[(size_t)(bn * 128 + r) * K + k0 + kc]);
        }
        __syncthreads();
#pragma unroll
        for (int kf = 0; kf < 2; ++kf) {
            short8 af[4], bf[4];
#pragma unroll
            for (int mi = 0; mi < 4; ++mi)
                af[mi] = *reinterpret_cast<const short8*>(
                    &aS[(wr * 64 + mi * 16 + l15) * 72 + kf * 32 + lq * 8]);
#pragma unroll
            for (int ni = 0; ni < 4; ++ni)
                bf[ni] = *reinterpret_cast<const short8*>(
                    &bS[(wc * 64 + ni * 16 + l15) * 72 + kf * 32 + lq * 8]);
#pragma unroll
            for (int mi = 0; mi < 4; ++mi)
#pragma unroll
                for (int ni = 0; ni < 4; ++ni)
                    acc[mi][ni] = __builtin_amdgcn_mfma_f32_16x16x32_bf16(
                        af[mi], bf[ni], acc[mi][ni], 0, 0, 0);
        }
        __syncthreads();
    }

#pragma unroll
    for (int mi = 0; mi < 4; ++mi) {
#pragma unroll
        for (int ni = 0; ni < 4; ++ni) {
#pragma unroll
            for (int i = 0; i < 4; ++i) {
                int m = bm * 128 + wr * 64 + mi * 16 + lq * 4 + i;
                int n = bn * 128 + wc * 64 + ni * 16 + l15;
                float v = acc[mi][ni][i] + bias[n];
                if (MODE == 0) {
                    int b = m >> 11, s = m & 2047, h = n >> 6, d = n & 63;
                    ((short*)out0)[((size_t)(b * 16 + h) * 2048 + s) * 64 + d] = f2bf(v * 0.125f);
                } else if (MODE == 1) {
                    int b = m >> 11, s = m & 2047, h = n >> 6, d = n & 63;
                    ((short*)out0)[((size_t)(b * 16 + h) * 2048 + s) * 64 + d] = f2bf(v);
                } else if (MODE == 2) {
                    int b = m >> 11, s = m & 2047, h = n >> 6, d = n & 63;
                    ((short*)out0)[((size_t)(b * 16 + h) * 64 + d) * 2048 + s] = f2bf(v);
                } else {
                    ((float*)out0)[(size_t)m * 1024 + n] = v;
                }
            }
        }
    }
}

// ---------------- causal flash attention ----------------
// grid = B*H*(S/128) = 512 blocks, 256 threads (4 waves, 32 q-rows each).
// q: [B,H,S,64] bf16 (pre-scaled by 0.125), k: [B,H,S,64], vT: [B,H,64,S]
// out attn: [B*S, 1024] bf16 (merged heads)
__global__ __launch_bounds__(256) void attn_fwd(
        const short* __restrict__ qh, const short* __restrict__ kh,
        const short* __restrict__ vT, short* __restrict__ attn) {
    __shared__ __align__(16) short kS[64 * 72];
    __shared__ __align__(16) short vS[64 * 72];
    __shared__ __align__(16) short pS[4][32 * 72];
    const int tid = threadIdx.x;
    const int lane = tid & 63;
    const int w = tid >> 6;
    const int l15 = lane & 15, lq = lane >> 4;
    const int qt = blockIdx.x & 15;   // S/128
    const int bh = blockIdx.x >> 4;   // 0..31
    const int b = bh >> 4, h = bh & 15;
    const size_t head = (size_t)(b * 16 + h) * 2048 * 64;
    const short* qp = qh + head;
    const short* kp = kh + head;
    const short* vp = vT + head;

    const int qw0 = qt * 128 + w * 32;

    short8 qf_[2][2];
#pragma unroll
    for (int qf = 0; qf < 2; ++qf)
#pragma unroll
        for (int kf = 0; kf < 2; ++kf)
            qf_[qf][kf] = *reinterpret_cast<const short8*>(
                &qp[(size_t)(qw0 + qf * 16 + l15) * 64 + kf * 32 + lq * 8]);

    f32x4 o[2][4] = {};
    float m_[2][4], l_[2][4];
#pragma unroll
    for (int qf = 0; qf < 2; ++qf)
#pragma unroll
        for (int i = 0; i < 4; ++i) { m_[qf][i] = -1e30f; l_[qf][i] = 0.f; }

    const int ntiles = qt * 2 + 2;
    for (int t = 0; t < ntiles; ++t) {
#pragma unroll
        for (int j = 0; j < 2; ++j) {
            int c = tid + 256 * j;
            int r = c >> 3, kc = (c & 7) << 3;
            *reinterpret_cast<short8*>(&kS[r * 72 + kc]) =
                *reinterpret_cast<const short8*>(&kp[(size_t)(t * 64 + r) * 64 + kc]);
            *reinterpret_cast<short8*>(&vS[r * 72 + kc]) =
                *reinterpret_cast<const short8*>(&vp[(size_t)r * 2048 + t * 64 + kc]);
        }
        __syncthreads();
        if (t * 64 <= qw0 + 31) {
            f32x4 s[2][4] = {};
#pragma unroll
            for (int kf = 0; kf < 2; ++kf) {
                short8 bf[4];
#pragma unroll
                for (int cf = 0; cf < 4; ++cf)
                    bf[cf] = *reinterpret_cast<const short8*>(
                        &kS[(cf * 16 + l15) * 72 + kf * 32 + lq * 8]);
#pragma unroll
                for (int qf = 0; qf < 2; ++qf)
#pragma unroll
                    for (int cf = 0; cf < 4; ++cf)
                        s[qf][cf] = __builtin_amdgcn_mfma_f32_16x16x32_bf16(
                            qf_[qf][kf], bf[cf], s[qf][cf], 0, 0, 0);
            }
            if (t * 64 + 63 > qw0) {
#pragma unroll
                for (int qf = 0; qf < 2; ++qf)
#pragma unroll
                    for (int cf = 0; cf < 4; ++cf)
#pragma unroll
                        for (int i = 0; i < 4; ++i) {
                            int qg = qw0 + qf * 16 + lq * 4 + i;
                            int kg = t * 64 + cf * 16 + l15;
                            if (kg > qg) s[qf][cf][i] = -1e30f;
                        }
            }
#pragma unroll
            for (int qf = 0; qf < 2; ++qf) {
                float mx[4], sc[4];
#pragma unroll
                for (int i = 0; i < 4; ++i) {
                    float v = fmaxf(fmaxf(s[qf][0][i], s[qf][1][i]),
                                    fmaxf(s[qf][2][i], s[qf][3][i]));
#pragma unroll
                    for (int x = 1; x < 16; x <<= 1) v = fmaxf(v, __shfl_xor(v, x));
                    float mn = fmaxf(m_[qf][i], v);
                    sc[i] = __expf(m_[qf][i] - mn);
                    m_[qf][i] = mn;
                    mx[i] = mn;
                }
                float rs[4] = {0.f, 0.f, 0.f, 0.f};
#pragma unroll
                for (int cf = 0; cf < 4; ++cf) {
#pragma unroll
                    for (int i = 0; i < 4; ++i) {
                        float p = __expf(s[qf][cf][i] - mx[i]);
                        rs[i] += p;
                        pS[w][(qf * 16 + lq * 4 + i) * 72 + cf * 16 + l15] = f2bf(p);
                    }
                }
#pragma unroll
                for (int i = 0; i < 4; ++i) {
                    float r = rs[i];
#pragma unroll
                    for (int x = 1; x < 16; x <<= 1) r += __shfl_xor(r, x);
                    l_[qf][i] = l_[qf][i] * sc[i] + r;
                }
#pragma unroll
                for (int df = 0; df < 4; ++df)
#pragma unroll
                    for (int i = 0; i < 4; ++i)
                        o[qf][df][i] *= sc[i];
            }
            asm volatile("s_waitcnt lgkmcnt(0)" ::: "memory");
            __builtin_amdgcn_sched_barrier(0);
#pragma unroll
            for (int kk = 0; kk < 2; ++kk) {
                short8 pa[2], vb[4];
#pragma unroll
                for (int qf = 0; qf < 2; ++qf)
                    pa[qf] = *reinterpret_cast<const short8*>(
                        &pS[w][(qf * 16 + l15) * 72 + kk * 32 + lq * 8]);
#pragma unroll
                for (int df = 0; df < 4; ++df)
                    vb[df] = *reinterpret_cast<const short8*>(
                        &vS[(df * 16 + l15) * 72 + kk * 32 + lq * 8]);
#pragma unroll
                for (int qf = 0; qf < 2; ++qf)
#pragma unroll
                    for (int df = 0; df < 4; ++df)
                        o[qf][df] = __builtin_amdgcn_mfma_f32_16x16x32_bf16(
                            pa[qf], vb[df], o[qf][df], 0, 0, 0);
            }
        }
        __syncthreads();
    }

#pragma unroll
    for (int qf = 0; qf < 2; ++qf) {
#pragma unroll
        for (int i = 0; i < 4; ++i) {
            float rinv = 1.0f / l_[qf][i];
            int sg = qw0 + qf * 16 + lq * 4 + i;
            size_t mrow = (size_t)b * 2048 + sg;
#pragma unroll
            for (int df = 0; df < 4; ++df) {
                int col = h * 64 + df * 16 + l15;
                attn[mrow * 1024 + col] = f2bf(o[qf][df][i] * rinv);
            }
        }
    }
}

extern "C" void kernel_launch(void* const* d_in, const int* in_sizes, int n_in,
                              void* d_out, int out_size, void* d_ws, size_t ws_size,
                              hipStream_t stream) {
    const float* Q  = (const float*)d_in[0];
    const float* K  = (const float*)d_in[1];
    const float* V  = (const float*)d_in[2];
    // d_in[3] = causal mask, not needed (applied analytically)
    const float* Wq = (const float*)d_in[4];
    const float* bq = (const float*)d_in[5];
    const float* Wk = (const float*)d_in[6];
    const float* bk = (const float*)d_in[7];
    const float* Wv = (const float*)d_in[8];
    const float* bv = (const float*)d_in[9];
    const float* Wo = (const float*)d_in[10];
    const float* bo = (const float*)d_in[11];

    char* ws = (char*)d_ws;
    short* Qb   = (short*)(ws);
    short* Kb   = (short*)(ws + 8388608);
    short* Vb   = (short*)(ws + 16777216);
    short* Wqb  = (short*)(ws + 25165824);
    short* Wkb  = (short*)(ws + 27262976);
    short* Wvb  = (short*)(ws + 29360128);
    short* Wob  = (short*)(ws + 31457280);
    short* q_   = (short*)(ws + 33554432);
    short* k_   = (short*)(ws + 41943040);
    short* vT   = (short*)(ws + 50331648);
    short* attn = Qb;  // Qb is dead after gemm_nt<0>; reuse for attention output

    dim3 cb(256);
    convert_f32_bf16<<<dim3(1024), cb, 0, stream>>>(Q, Qb, 4194304 / 4);
    convert_f32_bf16<<<dim3(1024), cb, 0, stream>>>(K, Kb, 4194304 / 4);
    convert_f32_bf16<<<dim3(1024), cb, 0, stream>>>(V, Vb, 4194304 / 4);
    convert_f32_bf16<<<dim3(512),  cb, 0, stream>>>(Wq, Wqb, 1048576 / 4);
    convert_f32_bf16<<<dim3(512),  cb, 0, stream>>>(Wk, Wkb, 1048576 / 4);
    convert_f32_bf16<<<dim3(512),  cb, 0, stream>>>(Wv, Wvb, 1048576 / 4);
    convert_f32_bf16<<<dim3(512),  cb, 0, stream>>>(Wo, Wob, 1048576 / 4);

    gemm_nt<0><<<dim3(256), cb, 0, stream>>>(Qb, Wqb, bq, (void*)q_);
    gemm_nt<1><<<dim3(256), cb, 0, stream>>>(Kb, Wkb, bk, (void*)k_);
    gemm_nt<2><<<dim3(256), cb, 0, stream>>>(Vb, Wvb, bv, (void*)vT);

    attn_fwd<<<dim3(512), cb, 0, stream>>>(q_, k_, vT, attn);

    gemm_nt<3><<<dim3(256), cb, 0, stream>>>(attn, Wob, bo, d_out);
}

// Round 2
// 295.535 us; speedup vs baseline: 1.1787x; 1.1787x over previous
//
#include <hip/hip_runtime.h>
#include <hip/hip_bf16.h>

typedef __attribute__((ext_vector_type(8))) short short8;
typedef __attribute__((ext_vector_type(4))) short short4v;
typedef __attribute__((ext_vector_type(4))) float f32x4;

static __device__ __forceinline__ short f2bf(float f) {
    __hip_bfloat16 h = __float2bfloat16(f);
    return __builtin_bit_cast(short, h);
}

#define GLOAD16(g, l) __builtin_amdgcn_global_load_lds( \
    (const __attribute__((address_space(1))) void*)(g), \
    (__attribute__((address_space(3))) void*)(l), 16, 0, 0)

// ---------------- fp32 -> bf16 converts (fused: grid.y picks array) ----------------
__global__ __launch_bounds__(256) void convert_qkv(
        const float* __restrict__ a, const float* __restrict__ b, const float* __restrict__ c,
        short* __restrict__ oa, short* __restrict__ ob, short* __restrict__ oc, int n4) {
    const float* in = blockIdx.y == 0 ? a : blockIdx.y == 1 ? b : c;
    short* out = blockIdx.y == 0 ? oa : blockIdx.y == 1 ? ob : oc;
    int i = blockIdx.x * blockDim.x + threadIdx.x;
    int stride = gridDim.x * blockDim.x;
    for (; i < n4; i += stride) {
        f32x4 v = reinterpret_cast<const f32x4*>(in)[i];
        short4v o;
        o.x = f2bf(v.x); o.y = f2bf(v.y); o.z = f2bf(v.z); o.w = f2bf(v.w);
        reinterpret_cast<short4v*>(out)[i] = o;
    }
}

__global__ __launch_bounds__(256) void convert_w(
        const float* __restrict__ a, const float* __restrict__ b,
        const float* __restrict__ c, const float* __restrict__ d,
        short* __restrict__ oa, short* __restrict__ ob,
        short* __restrict__ oc, short* __restrict__ od, int n4) {
    const float* in = blockIdx.y == 0 ? a : blockIdx.y == 1 ? b : blockIdx.y == 2 ? c : d;
    short* out = blockIdx.y == 0 ? oa : blockIdx.y == 1 ? ob : blockIdx.y == 2 ? oc : od;
    int i = blockIdx.x * blockDim.x + threadIdx.x;
    int stride = gridDim.x * blockDim.x;
    for (; i < n4; i += stride) {
        f32x4 v = reinterpret_cast<const f32x4*>(in)[i];
        short4v o;
        o.x = f2bf(v.x); o.y = f2bf(v.y); o.z = f2bf(v.z); o.w = f2bf(v.w);
        reinterpret_cast<short4v*>(out)[i] = o;
    }
}

// ---------------- NT GEMM: C[M,N] = A[M,K] @ W[N,K]^T + bias ----------------
// M=4096, N=1024, K=1024. 128x64 tile, 4 waves (2x2), BK=64, global_load_lds staging.
// grid = (M/128)*(N/64) = 512 blocks -> 2 blocks/CU.
// MODE 0: out = bf16 q head-split [B,H,S,64], value scaled by 0.125
// MODE 1: out = bf16 k head-split [B,H,S,64]
// MODE 2: out = bf16 v transposed  [B,H,64,S]
// MODE 3: out = fp32 [M,N]
template<int MODE>
__global__ __launch_bounds__(256) void gemm_nt(
        const short* __restrict__ A, const short* __restrict__ W,
        const float* __restrict__ bias, void* __restrict__ out0) {
    constexpr int K = 1024;
    __shared__ __align__(16) short aS[128 * 64];
    __shared__ __align__(16) short bS[64 * 64];
    const int tid = threadIdx.x;
    const int lane = tid & 63;
    const int w = tid >> 6;
    const int wr = w >> 1, wc = w & 1;
    const int bn = blockIdx.x & 15;  // N/64 = 16
    const int bm = blockIdx.x >> 4;  // M/128 = 32
    const int l15 = lane & 15, lq = lane >> 4;
    const int lr = lane >> 3;          // 0..7 rows per 1KB issue
    const int lc = (lane & 7) * 8;     // shorts

    f32x4 acc[4][2] = {};

    const short* Abase = &A[(size_t)(bm * 128) * K];
    const short* Wbase = &W[(size_t)(bn * 64) * K];

    for (int k0 = 0; k0 < K; k0 += 64) {
        // wave w stages A rows [w*32, w*32+32) (4 issues of 8 rows),
        // B rows [w*16, w*16+16) (2 issues)
#pragma unroll
        for (int j = 0; j < 4; ++j) {
            int r = w * 32 + j * 8;
            GLOAD16(&Abase[(size_t)(r + lr) * K + k0 + lc], &aS[r * 64]);
        }
#pragma unroll
        for (int j = 0; j < 2; ++j) {
            int r = w * 16 + j * 8;
            GLOAD16(&Wbase[(size_t)(r + lr) * K + k0 + lc], &bS[r * 64]);
        }
        __syncthreads();
#pragma unroll
        for (int kf = 0; kf < 2; ++kf) {
            short8 af[4], bf[2];
#pragma unroll
            for (int mi = 0; mi < 4; ++mi)
                af[mi] = *reinterpret_cast<const short8*>(
                    &aS[(wr * 64 + mi * 16 + l15) * 64 + kf * 32 + lq * 8]);
#pragma unroll
            for (int ni = 0; ni < 2; ++ni)
                bf[ni] = *reinterpret_cast<const short8*>(
                    &bS[(wc * 32 + ni * 16 + l15) * 64 + kf * 32 + lq * 8]);
#pragma unroll
            for (int mi = 0; mi < 4; ++mi)
#pragma unroll
                for (int ni = 0; ni < 2; ++ni)
                    acc[mi][ni] = __builtin_amdgcn_mfma_f32_16x16x32_bf16(
                        af[mi], bf[ni], acc[mi][ni], 0, 0, 0);
        }
        __syncthreads();
    }

#pragma unroll
    for (int mi = 0; mi < 4; ++mi) {
#pragma unroll
        for (int ni = 0; ni < 2; ++ni) {
#pragma unroll
            for (int i = 0; i < 4; ++i) {
                int m = bm * 128 + wr * 64 + mi * 16 + lq * 4 + i;
                int n = bn * 64 + wc * 32 + ni * 16 + l15;
                float v = acc[mi][ni][i] + bias[n];
                if (MODE == 0) {
                    int b = m >> 11, s = m & 2047, h = n >> 6, d = n & 63;
                    ((short*)out0)[((size_t)(b * 16 + h) * 2048 + s) * 64 + d] = f2bf(v * 0.125f);
                } else if (MODE == 1) {
                    int b = m >> 11, s = m & 2047, h = n >> 6, d = n & 63;
                    ((short*)out0)[((size_t)(b * 16 + h) * 2048 + s) * 64 + d] = f2bf(v);
                } else if (MODE == 2) {
                    int b = m >> 11, s = m & 2047, h = n >> 6, d = n & 63;
                    ((short*)out0)[((size_t)(b * 16 + h) * 64 + d) * 2048 + s] = f2bf(v);
                } else {
                    ((float*)out0)[(size_t)m * 1024 + n] = v;
                }
            }
        }
    }
}

// ---------------- causal flash attention ----------------
// grid = B*H*(S/64) = 1024 blocks, 256 threads (4 waves, 16 q-rows each).
// Heavy q-tiles launch first (qtile = 31 - bid>>5) for load balance.
// q: [B,H,S,64] bf16 (pre-scaled by 0.125), k: [B,H,S,64], vT: [B,H,64,S]
// out attn: [B*S, 1024] bf16 (merged heads)
__global__ __launch_bounds__(256) void attn_fwd(
        const short* __restrict__ qh, const short* __restrict__ kh,
        const short* __restrict__ vT, short* __restrict__ attn) {
    __shared__ __align__(16) short kS[64 * 72];
    __shared__ __align__(16) short vS[64 * 72];
    __shared__ __align__(16) short pS[4][16 * 72];
    const int tid = threadIdx.x;
    const int lane = tid & 63;
    const int w = tid >> 6;
    const int l15 = lane & 15, lq = lane >> 4;
    const int bh = blockIdx.x & 31;            // 0..31 (b*16+h)
    const int qtile = 31 - (blockIdx.x >> 5);  // heavy first
    const int b = bh >> 4, h = bh & 15;
    const size_t head = (size_t)bh * 2048 * 64;
    const short* qp = qh + head;
    const short* kp = kh + head;
    const short* vp = vT + head;

    const int qw0 = qtile * 64 + w * 16;  // this wave's first q row

    short8 qf_[2];
#pragma unroll
    for (int kf = 0; kf < 2; ++kf)
        qf_[kf] = *reinterpret_cast<const short8*>(
            &qp[(size_t)(qw0 + l15) * 64 + kf * 32 + lq * 8]);

    f32x4 o[4] = {};
    float m_[4], l_[4];
#pragma unroll
    for (int i = 0; i < 4; ++i) { m_[i] = -1e30f; l_[i] = 0.f; }

    const int ntiles = qtile + 1;
    for (int t = 0; t < ntiles; ++t) {
#pragma unroll
        for (int j = 0; j < 2; ++j) {
            int c = tid + 256 * j;
            int r = c >> 3, kc = (c & 7) << 3;
            *reinterpret_cast<short8*>(&kS[r * 72 + kc]) =
                *reinterpret_cast<const short8*>(&kp[(size_t)(t * 64 + r) * 64 + kc]);
            *reinterpret_cast<short8*>(&vS[r * 72 + kc]) =
                *reinterpret_cast<const short8*>(&vp[(size_t)r * 2048 + t * 64 + kc]);
        }
        __syncthreads();
        {
            f32x4 s[4] = {};
#pragma unroll
            for (int kf = 0; kf < 2; ++kf) {
                short8 bf[4];
#pragma unroll
                for (int cf = 0; cf < 4; ++cf)
                    bf[cf] = *reinterpret_cast<const short8*>(
                        &kS[(cf * 16 + l15) * 72 + kf * 32 + lq * 8]);
#pragma unroll
                for (int cf = 0; cf < 4; ++cf)
                    s[cf] = __builtin_amdgcn_mfma_f32_16x16x32_bf16(
                        qf_[kf], bf[cf], s[cf], 0, 0, 0);
            }
            if (t == qtile) {  // diagonal tile: causal mask
#pragma unroll
                for (int cf = 0; cf < 4; ++cf)
#pragma unroll
                    for (int i = 0; i < 4; ++i) {
                        int qg = qw0 + lq * 4 + i;
                        int kg = t * 64 + cf * 16 + l15;
                        if (kg > qg) s[cf][i] = -1e30f;
                    }
            }
            float mx[4], sc[4];
#pragma unroll
            for (int i = 0; i < 4; ++i) {
                float v = fmaxf(fmaxf(s[0][i], s[1][i]), fmaxf(s[2][i], s[3][i]));
#pragma unroll
                for (int x = 1; x < 16; x <<= 1) v = fmaxf(v, __shfl_xor(v, x));
                float mn = fmaxf(m_[i], v);
                sc[i] = __expf(m_[i] - mn);
                m_[i] = mn;
                mx[i] = mn;
            }
            float rs[4] = {0.f, 0.f, 0.f, 0.f};
#pragma unroll
            for (int cf = 0; cf < 4; ++cf) {
#pragma unroll
                for (int i = 0; i < 4; ++i) {
                    float p = __expf(s[cf][i] - mx[i]);
                    rs[i] += p;
                    pS[w][(lq * 4 + i) * 72 + cf * 16 + l15] = f2bf(p);
                }
            }
#pragma unroll
            for (int i = 0; i < 4; ++i) {
                float r = rs[i];
#pragma unroll
                for (int x = 1; x < 16; x <<= 1) r += __shfl_xor(r, x);
                l_[i] = l_[i] * sc[i] + r;
            }
#pragma unroll
            for (int df = 0; df < 4; ++df)
#pragma unroll
                for (int i = 0; i < 4; ++i)
                    o[df][i] *= sc[i];
            asm volatile("s_waitcnt lgkmcnt(0)" ::: "memory");
            __builtin_amdgcn_sched_barrier(0);
#pragma unroll
            for (int kk = 0; kk < 2; ++kk) {
                short8 pa, vb[4];
                pa = *reinterpret_cast<const short8*>(
                    &pS[w][l15 * 72 + kk * 32 + lq * 8]);
#pragma unroll
                for (int df = 0; df < 4; ++df)
                    vb[df] = *reinterpret_cast<const short8*>(
                        &vS[(df * 16 + l15) * 72 + kk * 32 + lq * 8]);
#pragma unroll
                for (int df = 0; df < 4; ++df)
                    o[df] = __builtin_amdgcn_mfma_f32_16x16x32_bf16(
                        pa, vb[df], o[df], 0, 0, 0);
            }
        }
        __syncthreads();
    }

#pragma unroll
    for (int i = 0; i < 4; ++i) {
        float rinv = 1.0f / l_[i];
        int sg = qw0 + lq * 4 + i;
        size_t mrow = (size_t)b * 2048 + sg;
#pragma unroll
        for (int df = 0; df < 4; ++df) {
            int col = h * 64 + df * 16 + l15;
            attn[mrow * 1024 + col] = f2bf(o[df][i] * rinv);
        }
    }
}

extern "C" void kernel_launch(void* const* d_in, const int* in_sizes, int n_in,
                              void* d_out, int out_size, void* d_ws, size_t ws_size,
                              hipStream_t stream) {
    const float* Q  = (const float*)d_in[0];
    const float* K  = (const float*)d_in[1];
    const float* V  = (const float*)d_in[2];
    // d_in[3] = causal mask, applied analytically
    const float* Wq = (const float*)d_in[4];
    const float* bq = (const float*)d_in[5];
    const float* Wk = (const float*)d_in[6];
    const float* bk = (const float*)d_in[7];
    const float* Wv = (const float*)d_in[8];
    const float* bv = (const float*)d_in[9];
    const float* Wo = (const float*)d_in[10];
    const float* bo = (const float*)d_in[11];

    char* ws = (char*)d_ws;
    short* Qb   = (short*)(ws);
    short* Kb   = (short*)(ws + 8388608);
    short* Vb   = (short*)(ws + 16777216);
    short* Wqb  = (short*)(ws + 25165824);
    short* Wkb  = (short*)(ws + 27262976);
    short* Wvb  = (short*)(ws + 29360128);
    short* Wob  = (short*)(ws + 31457280);
    short* q_   = (short*)(ws + 33554432);
    short* k_   = (short*)(ws + 41943040);
    short* vT   = (short*)(ws + 50331648);
    short* attn = Qb;  // Qb dead after gemm_nt<0>; reuse for attention output

    dim3 cb(256);
    convert_qkv<<<dim3(1024, 3), cb, 0, stream>>>(Q, K, V, Qb, Kb, Vb, 4194304 / 4);
    convert_w<<<dim3(512, 4), cb, 0, stream>>>(Wq, Wk, Wv, Wo, Wqb, Wkb, Wvb, Wob, 1048576 / 4);

    gemm_nt<0><<<dim3(512), cb, 0, stream>>>(Qb, Wqb, bq, (void*)q_);
    gemm_nt<1><<<dim3(512), cb, 0, stream>>>(Kb, Wkb, bk, (void*)k_);
    gemm_nt<2><<<dim3(512), cb, 0, stream>>>(Vb, Wvb, bv, (void*)vT);

    attn_fwd<<<dim3(1024), cb, 0, stream>>>(q_, k_, vT, attn);

    gemm_nt<3><<<dim3(512), cb, 0, stream>>>(attn, Wob, bo, d_out);
}

// Round 3
// 263.671 us; speedup vs baseline: 1.3212x; 1.1208x over previous
//
#include <hip/hip_runtime.h>
#include <hip/hip_bf16.h>

typedef __attribute__((ext_vector_type(8))) short short8;
typedef __attribute__((ext_vector_type(4))) short short4v;
typedef __attribute__((ext_vector_type(4))) float f32x4;

static __device__ __forceinline__ short f2bf(float f) {
    __hip_bfloat16 h = __float2bfloat16(f);
    return __builtin_bit_cast(short, h);
}

#define GLOAD16(g, l) __builtin_amdgcn_global_load_lds( \
    (const __attribute__((address_space(1))) void*)(g), \
    (__attribute__((address_space(3))) void*)(l), 16, 0, 0)

// ---------------- fp32 -> bf16 converts ----------------
__global__ __launch_bounds__(256) void convert_qkv(
        const float* __restrict__ a, const float* __restrict__ b, const float* __restrict__ c,
        short* __restrict__ oa, short* __restrict__ ob, short* __restrict__ oc, int n4) {
    const float* in = blockIdx.y == 0 ? a : blockIdx.y == 1 ? b : c;
    short* out = blockIdx.y == 0 ? oa : blockIdx.y == 1 ? ob : oc;
    int i = blockIdx.x * blockDim.x + threadIdx.x;
    int stride = gridDim.x * blockDim.x;
    for (; i < n4; i += stride) {
        f32x4 v = reinterpret_cast<const f32x4*>(in)[i];
        short4v o;
        o.x = f2bf(v.x); o.y = f2bf(v.y); o.z = f2bf(v.z); o.w = f2bf(v.w);
        reinterpret_cast<short4v*>(out)[i] = o;
    }
}

__global__ __launch_bounds__(256) void convert_w(
        const float* __restrict__ a, const float* __restrict__ b,
        const float* __restrict__ c, const float* __restrict__ d,
        short* __restrict__ oa, short* __restrict__ ob,
        short* __restrict__ oc, short* __restrict__ od, int n4) {
    const float* in = blockIdx.y == 0 ? a : blockIdx.y == 1 ? b : blockIdx.y == 2 ? c : d;
    short* out = blockIdx.y == 0 ? oa : blockIdx.y == 1 ? ob : blockIdx.y == 2 ? oc : od;
    int i = blockIdx.x * blockDim.x + threadIdx.x;
    int stride = gridDim.x * blockDim.x;
    for (; i < n4; i += stride) {
        f32x4 v = reinterpret_cast<const f32x4*>(in)[i];
        short4v o;
        o.x = f2bf(v.x); o.y = f2bf(v.y); o.z = f2bf(v.z); o.w = f2bf(v.w);
        reinterpret_cast<short4v*>(out)[i] = o;
    }
}

// ---------------- shared GEMM K-loop ----------------
// C[128x64 tile] = A[128,1024] @ W[64,1024]^T. Double-buffered gload_lds,
// counted vmcnt(6), raw barriers, T2 both-sides XOR swizzle (16B chunk ^ row&7).
__device__ __forceinline__ void gemm_kloop(
        const short* __restrict__ Abase, const short* __restrict__ Wbase,
        short* aSb, short* bSb, f32x4 (&acc)[4][2], int w, int lane) {
    const int lr = lane >> 3;
    const int lcs = ((lane & 7) ^ lr) * 8;   // pre-swizzled global col (shorts)
    const int l15 = lane & 15, lq = lane >> 4;
    const int wr = w >> 1, wc = w & 1;
    const int cA0 = ((0 + lq) ^ (l15 & 7)) * 8;   // swizzled ds_read col, kf=0
    const int cA1 = ((4 + lq) ^ (l15 & 7)) * 8;   // kf=1

    // prologue: stage tile 0 into buf 0
#pragma unroll
    for (int j = 0; j < 4; ++j) {
        int r0 = w * 32 + j * 8;
        GLOAD16(&Abase[(size_t)(r0 + lr) * 1024 + lcs], &aSb[r0 * 64]);
    }
#pragma unroll
    for (int j = 0; j < 2; ++j) {
        int r0 = w * 16 + j * 8;
        GLOAD16(&Wbase[(size_t)(r0 + lr) * 1024 + lcs], &bSb[r0 * 64]);
    }

    for (int t = 0; t < 16; ++t) {
        const int cur = t & 1;
        if (t < 15) {
            const int k0 = (t + 1) * 64;
            const int nb = cur ^ 1;
#pragma unroll
            for (int j = 0; j < 4; ++j) {
                int r0 = w * 32 + j * 8;
                GLOAD16(&Abase[(size_t)(r0 + lr) * 1024 + k0 + lcs], &aSb[nb * 8192 + r0 * 64]);
            }
#pragma unroll
            for (int j = 0; j < 2; ++j) {
                int r0 = w * 16 + j * 8;
                GLOAD16(&Wbase[(size_t)(r0 + lr) * 1024 + k0 + lcs], &bSb[nb * 4096 + r0 * 64]);
            }
            asm volatile("s_waitcnt vmcnt(6)" ::: "memory");  // current tile landed, next in flight
        } else {
            asm volatile("s_waitcnt vmcnt(0)" ::: "memory");
        }
        __builtin_amdgcn_s_barrier();
        __builtin_amdgcn_sched_barrier(0);
#pragma unroll
        for (int kf = 0; kf < 2; ++kf) {
            const int ck = kf ? cA1 : cA0;
            short8 af[4], bfr[2];
#pragma unroll
            for (int mi = 0; mi < 4; ++mi)
                af[mi] = *reinterpret_cast<const short8*>(
                    &aSb[cur * 8192 + (wr * 64 + mi * 16 + l15) * 64 + ck]);
#pragma unroll
            for (int ni = 0; ni < 2; ++ni)
                bfr[ni] = *reinterpret_cast<const short8*>(
                    &bSb[cur * 4096 + (wc * 32 + ni * 16 + l15) * 64 + ck]);
#pragma unroll
            for (int mi = 0; mi < 4; ++mi)
#pragma unroll
                for (int ni = 0; ni < 2; ++ni)
                    acc[mi][ni] = __builtin_amdgcn_mfma_f32_16x16x32_bf16(
                        af[mi], bfr[ni], acc[mi][ni], 0, 0, 0);
        }
        asm volatile("s_waitcnt lgkmcnt(0)" ::: "memory");
        __builtin_amdgcn_sched_barrier(0);
        __builtin_amdgcn_s_barrier();
    }
}

// ---------------- fused QKV projection GEMM ----------------
// grid = (512, 3): x -> 128x64 tile (XCD-swizzled), y -> {Q,K,V}
__global__ __launch_bounds__(256, 3) void gemm_qkv(
        const short* __restrict__ Qb, const short* __restrict__ Kb, const short* __restrict__ Vb,
        const short* __restrict__ Wq, const short* __restrict__ Wk, const short* __restrict__ Wv,
        const float* __restrict__ bq, const float* __restrict__ bk, const float* __restrict__ bv,
        short* __restrict__ q_, short* __restrict__ k_, short* __restrict__ vT) {
    __shared__ __align__(16) short aSb[2 * 128 * 64];
    __shared__ __align__(16) short bSb[2 * 64 * 64];
    const int tid = threadIdx.x;
    const int lane = tid & 63;
    const int w = tid >> 6;
    const int y = blockIdx.y;
    const int wg = (blockIdx.x & 7) * 64 + (blockIdx.x >> 3);  // XCD swizzle (512%8==0)
    const int bn = wg & 15;   // N/64 = 16
    const int bm = wg >> 4;   // M/128 = 32
    const int l15 = lane & 15, lq = lane >> 4;
    const int wr = w >> 1, wc = w & 1;

    const short* A = y == 0 ? Qb : y == 1 ? Kb : Vb;
    const short* W = y == 0 ? Wq : y == 1 ? Wk : Wv;
    const float* bias = y == 0 ? bq : y == 1 ? bk : bv;

    f32x4 acc[4][2] = {};
    gemm_kloop(&A[(size_t)(bm * 128) * 1024], &W[(size_t)(bn * 64) * 1024],
               aSb, bSb, acc, w, lane);

#pragma unroll
    for (int mi = 0; mi < 4; ++mi) {
#pragma unroll
        for (int ni = 0; ni < 2; ++ni) {
#pragma unroll
            for (int i = 0; i < 4; ++i) {
                int m = bm * 128 + wr * 64 + mi * 16 + lq * 4 + i;
                int n = bn * 64 + wc * 32 + ni * 16 + l15;
                float v = acc[mi][ni][i] + bias[n];
                int b = m >> 11, s = m & 2047, h = n >> 6, d = n & 63;
                if (y == 0) {
                    q_[((size_t)(b * 16 + h) * 2048 + s) * 64 + d] = f2bf(v * 0.125f);
                } else if (y == 1) {
                    k_[((size_t)(b * 16 + h) * 2048 + s) * 64 + d] = f2bf(v);
                } else {
                    vT[((size_t)(b * 16 + h) * 64 + d) * 2048 + s] = f2bf(v);
                }
            }
        }
    }
}

// ---------------- output projection GEMM (fp32 out) ----------------
__global__ __launch_bounds__(256, 3) void gemm_o(
        const short* __restrict__ A, const short* __restrict__ W,
        const float* __restrict__ bias, float* __restrict__ out) {
    __shared__ __align__(16) short aSb[2 * 128 * 64];
    __shared__ __align__(16) short bSb[2 * 64 * 64];
    const int tid = threadIdx.x;
    const int lane = tid & 63;
    const int w = tid >> 6;
    const int wg = (blockIdx.x & 7) * 64 + (blockIdx.x >> 3);
    const int bn = wg & 15;
    const int bm = wg >> 4;
    const int l15 = lane & 15, lq = lane >> 4;
    const int wr = w >> 1, wc = w & 1;

    f32x4 acc[4][2] = {};
    gemm_kloop(&A[(size_t)(bm * 128) * 1024], &W[(size_t)(bn * 64) * 1024],
               aSb, bSb, acc, w, lane);

#pragma unroll
    for (int mi = 0; mi < 4; ++mi)
#pragma unroll
        for (int ni = 0; ni < 2; ++ni)
#pragma unroll
            for (int i = 0; i < 4; ++i) {
                int m = bm * 128 + wr * 64 + mi * 16 + lq * 4 + i;
                int n = bn * 64 + wc * 32 + ni * 16 + l15;
                out[(size_t)m * 1024 + n] = acc[mi][ni][i] + bias[n];
            }
}

// ---------------- causal flash attention ----------------
// grid = 512 (32 bh x 16 qtiles, heavy-first), 512 threads = 8 waves, 16 q-rows/wave.
// K/V double-buffered in LDS, reg-staged issue-early/write-late (T14).
__global__ __launch_bounds__(512, 4) void attn_fwd(
        const short* __restrict__ qh, const short* __restrict__ kh,
        const short* __restrict__ vT, short* __restrict__ attn) {
    __shared__ __align__(16) short kS[2][64 * 72];
    __shared__ __align__(16) short vS[2][64 * 72];
    __shared__ __align__(16) short pS[8][16 * 72];
    const int tid = threadIdx.x;
    const int lane = tid & 63;
    const int w = tid >> 6;                    // 0..7
    const int l15 = lane & 15, lq = lane >> 4;
    const int bh = blockIdx.x & 31;            // b*16+h (same bh -> same XCD)
    const int qt = 15 - (blockIdx.x >> 5);     // heavy-first
    const int b = bh >> 4, h = bh & 15;
    const size_t head = (size_t)bh * 2048 * 64;
    const short* qp = qh + head;
    const short* kp = kh + head;
    const short* vp = vT + head;

    const int qw0 = qt * 128 + w * 16;         // this wave's first q row

    short8 qf_[2];
#pragma unroll
    for (int kf = 0; kf < 2; ++kf)
        qf_[kf] = *reinterpret_cast<const short8*>(
            &qp[(size_t)(qw0 + l15) * 64 + kf * 32 + lq * 8]);

    f32x4 o[4] = {};
    float m_[4], l_[4];
#pragma unroll
    for (int i = 0; i < 4; ++i) { m_[i] = -1e30f; l_[i] = 0.f; }

    // staging share: each of 512 threads owns one short8 of K and one of V
    const int sr = tid >> 3;            // 0..63 (row)
    const int sc = (tid & 7) * 8;       // col (shorts)

    const int nt = 2 * qt + 2;
    // prologue: stage tile 0
    short8 kreg = *reinterpret_cast<const short8*>(&kp[(size_t)sr * 64 + sc]);
    short8 vreg = *reinterpret_cast<const short8*>(&vp[(size_t)sr * 2048 + sc]);
    *reinterpret_cast<short8*>(&kS[0][sr * 72 + sc]) = kreg;
    *reinterpret_cast<short8*>(&vS[0][sr * 72 + sc]) = vreg;
    __syncthreads();

    for (int t = 0; t < nt; ++t) {
        const int p = t & 1;
        if (t + 1 < nt) {  // issue-early: next tile global loads
            kreg = *reinterpret_cast<const short8*>(
                &kp[(size_t)((t + 1) * 64 + sr) * 64 + sc]);
            vreg = *reinterpret_cast<const short8*>(
                &vp[(size_t)sr * 2048 + (t + 1) * 64 + sc]);
        }
        if (t * 64 <= qw0 + 15) {  // this wave has unmasked work in tile t
            f32x4 s[4] = {};
#pragma unroll
            for (int kf = 0; kf < 2; ++kf) {
                short8 bfr[4];
#pragma unroll
                for (int cf = 0; cf < 4; ++cf)
                    bfr[cf] = *reinterpret_cast<const short8*>(
                        &kS[p][(cf * 16 + l15) * 72 + kf * 32 + lq * 8]);
#pragma unroll
                for (int cf = 0; cf < 4; ++cf)
                    s[cf] = __builtin_amdgcn_mfma_f32_16x16x32_bf16(
                        qf_[kf], bfr[cf], s[cf], 0, 0, 0);
            }
            if (t * 64 + 63 > qw0) {  // diagonal: causal mask
#pragma unroll
                for (int cf = 0; cf < 4; ++cf)
#pragma unroll
                    for (int i = 0; i < 4; ++i) {
                        int qg = qw0 + lq * 4 + i;
                        int kg = t * 64 + cf * 16 + l15;
                        if (kg > qg) s[cf][i] = -1e30f;
                    }
            }
            float mx[4], scale[4];
#pragma unroll
            for (int i = 0; i < 4; ++i) {
                float v = fmaxf(fmaxf(s[0][i], s[1][i]), fmaxf(s[2][i], s[3][i]));
#pragma unroll
                for (int x = 1; x < 16; x <<= 1) v = fmaxf(v, __shfl_xor(v, x));
                float mn = fmaxf(m_[i], v);
                scale[i] = __expf(m_[i] - mn);
                m_[i] = mn;
                mx[i] = mn;
            }
            float rs[4] = {0.f, 0.f, 0.f, 0.f};
#pragma unroll
            for (int cf = 0; cf < 4; ++cf) {
#pragma unroll
                for (int i = 0; i < 4; ++i) {
                    float pv = __expf(s[cf][i] - mx[i]);
                    rs[i] += pv;
                    pS[w][(lq * 4 + i) * 72 + cf * 16 + l15] = f2bf(pv);
                }
            }
#pragma unroll
            for (int i = 0; i < 4; ++i) {
                float r = rs[i];
#pragma unroll
                for (int x = 1; x < 16; x <<= 1) r += __shfl_xor(r, x);
                l_[i] = l_[i] * scale[i] + r;
            }
#pragma unroll
            for (int df = 0; df < 4; ++df)
#pragma unroll
                for (int i = 0; i < 4; ++i)
                    o[df][i] *= scale[i];
            asm volatile("s_waitcnt lgkmcnt(0)" ::: "memory");
            __builtin_amdgcn_sched_barrier(0);
#pragma unroll
            for (int kk = 0; kk < 2; ++kk) {
                short8 pa, vb[4];
                pa = *reinterpret_cast<const short8*>(
                    &pS[w][l15 * 72 + kk * 32 + lq * 8]);
#pragma unroll
                for (int df = 0; df < 4; ++df)
                    vb[df] = *reinterpret_cast<const short8*>(
                        &vS[p][(df * 16 + l15) * 72 + kk * 32 + lq * 8]);
#pragma unroll
                for (int df = 0; df < 4; ++df)
                    o[df] = __builtin_amdgcn_mfma_f32_16x16x32_bf16(
                        pa, vb[df], o[df], 0, 0, 0);
            }
        }
        if (t + 1 < nt) {  // write-late: next tile into other buffer
            *reinterpret_cast<short8*>(&kS[p ^ 1][sr * 72 + sc]) = kreg;
            *reinterpret_cast<short8*>(&vS[p ^ 1][sr * 72 + sc]) = vreg;
        }
        __syncthreads();
    }

#pragma unroll
    for (int i = 0; i < 4; ++i) {
        float rinv = 1.0f / l_[i];
        int sg = qw0 + lq * 4 + i;
        size_t mrow = (size_t)b * 2048 + sg;
#pragma unroll
        for (int df = 0; df < 4; ++df) {
            int col = h * 64 + df * 16 + l15;
            attn[mrow * 1024 + col] = f2bf(o[df][i] * rinv);
        }
    }
}

extern "C" void kernel_launch(void* const* d_in, const int* in_sizes, int n_in,
                              void* d_out, int out_size, void* d_ws, size_t ws_size,
                              hipStream_t stream) {
    const float* Q  = (const float*)d_in[0];
    const float* K  = (const float*)d_in[1];
    const float* V  = (const float*)d_in[2];
    // d_in[3] = causal mask, applied analytically
    const float* Wq = (const float*)d_in[4];
    const float* bq = (const float*)d_in[5];
    const float* Wk = (const float*)d_in[6];
    const float* bk = (const float*)d_in[7];
    const float* Wv = (const float*)d_in[8];
    const float* bv = (const float*)d_in[9];
    const float* Wo = (const float*)d_in[10];
    const float* bo = (const float*)d_in[11];

    char* ws = (char*)d_ws;
    short* Qb   = (short*)(ws);
    short* Kb   = (short*)(ws + 8388608);
    short* Vb   = (short*)(ws + 16777216);
    short* Wqb  = (short*)(ws + 25165824);
    short* Wkb  = (short*)(ws + 27262976);
    short* Wvb  = (short*)(ws + 29360128);
    short* Wob  = (short*)(ws + 31457280);
    short* q_   = (short*)(ws + 33554432);
    short* k_   = (short*)(ws + 41943040);
    short* vT   = (short*)(ws + 50331648);
    short* attn = Qb;  // Qb dead after gemm_qkv; reuse for attention output

    dim3 cb(256);
    convert_qkv<<<dim3(1024, 3), cb, 0, stream>>>(Q, K, V, Qb, Kb, Vb, 4194304 / 4);
    convert_w<<<dim3(512, 4), cb, 0, stream>>>(Wq, Wk, Wv, Wo, Wqb, Wkb, Wvb, Wob, 1048576 / 4);

    gemm_qkv<<<dim3(512, 3), cb, 0, stream>>>(Qb, Kb, Vb, Wqb, Wkb, Wvb,
                                              bq, bk, bv, q_, k_, vT);

    attn_fwd<<<dim3(512), dim3(512), 0, stream>>>(q_, k_, vT, attn);

    gemm_o<<<dim3(512), cb, 0, stream>>>(attn, Wob, bo, (float*)d_out);
}

// Round 5
// 227.870 us; speedup vs baseline: 1.5287x; 1.1571x over previous
//
#include <hip/hip_runtime.h>
#include <hip/hip_bf16.h>

typedef __attribute__((ext_vector_type(8))) short short8;
typedef __attribute__((ext_vector_type(4))) short short4v;
typedef __attribute__((ext_vector_type(4))) float f32x4;

static __device__ __forceinline__ short f2bf(float f) {
    __hip_bfloat16 h = __float2bfloat16(f);
    return __builtin_bit_cast(short, h);
}

// v_exp_f32 computes 2^x directly (scores pre-scaled by log2e)
static __device__ __forceinline__ float exp2fast(float x) {
    float r;
    asm("v_exp_f32 %0, %1" : "=v"(r) : "v"(x));
    return r;
}

// pack two f32 -> two bf16 in one dword (lo=a, hi=b)
static __device__ __forceinline__ unsigned cvt_pk_bf16(float a, float b) {
    unsigned r;
    asm("v_cvt_pk_bf16_f32 %0, %1, %2" : "=v"(r) : "v"(a), "v"(b));
    return r;
}

#define GLOAD16(g, l) __builtin_amdgcn_global_load_lds( \
    (const __attribute__((address_space(1))) void*)(g), \
    (__attribute__((address_space(3))) void*)(l), 16, 0, 0)

// ---------------- fp32 -> bf16 converts ----------------
__global__ __launch_bounds__(256) void convert_qkv(
        const float* __restrict__ a, const float* __restrict__ b, const float* __restrict__ c,
        short* __restrict__ oa, short* __restrict__ ob, short* __restrict__ oc, int n4) {
    const float* in = blockIdx.y == 0 ? a : blockIdx.y == 1 ? b : c;
    short* out = blockIdx.y == 0 ? oa : blockIdx.y == 1 ? ob : oc;
    int i = blockIdx.x * blockDim.x + threadIdx.x;
    int stride = gridDim.x * blockDim.x;
    for (; i < n4; i += stride) {
        f32x4 v = reinterpret_cast<const f32x4*>(in)[i];
        short4v o;
        o.x = f2bf(v.x); o.y = f2bf(v.y); o.z = f2bf(v.z); o.w = f2bf(v.w);
        reinterpret_cast<short4v*>(out)[i] = o;
    }
}

__global__ __launch_bounds__(256) void convert_w(
        const float* __restrict__ a, const float* __restrict__ b,
        const float* __restrict__ c, const float* __restrict__ d,
        short* __restrict__ oa, short* __restrict__ ob,
        short* __restrict__ oc, short* __restrict__ od, int n4) {
    const float* in = blockIdx.y == 0 ? a : blockIdx.y == 1 ? b : blockIdx.y == 2 ? c : d;
    short* out = blockIdx.y == 0 ? oa : blockIdx.y == 1 ? ob : blockIdx.y == 2 ? oc : od;
    int i = blockIdx.x * blockDim.x + threadIdx.x;
    int stride = gridDim.x * blockDim.x;
    for (; i < n4; i += stride) {
        f32x4 v = reinterpret_cast<const f32x4*>(in)[i];
        short4v o;
        o.x = f2bf(v.x); o.y = f2bf(v.y); o.z = f2bf(v.z); o.w = f2bf(v.w);
        reinterpret_cast<short4v*>(out)[i] = o;
    }
}

// ---------------- fused QKV projection GEMM (m97 structure) ----------------
// 128x128 tile, 4 waves (2x2, 64x64 each, 4x4 acc), BK=64 single-buffered
// gload_lds w/ both-sides XOR swizzle. grid = (256, 3), 3 blocks/CU.
__global__ __launch_bounds__(256, 3) void gemm_qkv(
        const short* __restrict__ Qb, const short* __restrict__ Kb, const short* __restrict__ Vb,
        const short* __restrict__ Wq, const short* __restrict__ Wk, const short* __restrict__ Wv,
        const float* __restrict__ bq, const float* __restrict__ bk, const float* __restrict__ bv,
        short* __restrict__ q_, short* __restrict__ k_, short* __restrict__ vT) {
    __shared__ __align__(16) short aS[128 * 64];
    __shared__ __align__(16) short bS[128 * 64];
    const int tid = threadIdx.x;
    const int lane = tid & 63;
    const int w = tid >> 6;
    const int wr = w >> 1, wc = w & 1;
    const int l15 = lane & 15, lq = lane >> 4;
    const int lr = lane >> 3;
    const int lcs = ((lane & 7) ^ lr) * 8;   // pre-swizzled global col (shorts)
    const int y = blockIdx.y;
    const int wg = (blockIdx.x & 7) * 32 + (blockIdx.x >> 3);  // XCD swizzle (256%8==0)
    const int bn = wg & 7;    // N/128 = 8
    const int bm = wg >> 3;   // M/128 = 32

    const short* A = y == 0 ? Qb : y == 1 ? Kb : Vb;
    const short* W = y == 0 ? Wq : y == 1 ? Wk : Wv;
    const float* bias = y == 0 ? bq : y == 1 ? bk : bv;
    const short* Ab = A + (size_t)(bm * 128) * 1024;
    const short* Wb = W + (size_t)(bn * 128) * 1024;

    f32x4 acc[4][4] = {};

    for (int t = 0; t < 16; ++t) {
        const int k0 = t * 64;
#pragma unroll
        for (int j = 0; j < 4; ++j) {
            int r0 = w * 32 + j * 8;
            GLOAD16(&Ab[(size_t)(r0 + lr) * 1024 + k0 + lcs], &aS[r0 * 64]);
        }
#pragma unroll
        for (int j = 0; j < 4; ++j) {
            int r0 = w * 32 + j * 8;
            GLOAD16(&Wb[(size_t)(r0 + lr) * 1024 + k0 + lcs], &bS[r0 * 64]);
        }
        asm volatile("s_waitcnt vmcnt(0)" ::: "memory");
        __builtin_amdgcn_s_barrier();
#pragma unroll
        for (int kf = 0; kf < 2; ++kf) {
            const int ck = ((kf * 4 + lq) ^ (l15 & 7)) * 8;
            short8 af[4], bfr[4];
#pragma unroll
            for (int mi = 0; mi < 4; ++mi)
                af[mi] = *reinterpret_cast<const short8*>(
                    &aS[(wr * 64 + mi * 16 + l15) * 64 + ck]);
#pragma unroll
            for (int ni = 0; ni < 4; ++ni)
                bfr[ni] = *reinterpret_cast<const short8*>(
                    &bS[(wc * 64 + ni * 16 + l15) * 64 + ck]);
#pragma unroll
            for (int mi = 0; mi < 4; ++mi)
#pragma unroll
                for (int ni = 0; ni < 4; ++ni)
                    acc[mi][ni] = __builtin_amdgcn_mfma_f32_16x16x32_bf16(
                        af[mi], bfr[ni], acc[mi][ni], 0, 0, 0);
        }
        asm volatile("s_waitcnt lgkmcnt(0)" ::: "memory");
        __builtin_amdgcn_sched_barrier(0);
        __builtin_amdgcn_s_barrier();
    }

    // q pre-scaled by 1/sqrt(64) * log2(e) so attention scores are log2-domain
    const float QSCALE = 0.125f * 1.44269504f;
#pragma unroll
    for (int mi = 0; mi < 4; ++mi) {
#pragma unroll
        for (int ni = 0; ni < 4; ++ni) {
#pragma unroll
            for (int i = 0; i < 4; ++i) {
                int m = bm * 128 + wr * 64 + mi * 16 + lq * 4 + i;
                int n = bn * 128 + wc * 64 + ni * 16 + l15;
                float v = acc[mi][ni][i] + bias[n];
                int b = m >> 11, s = m & 2047, h = n >> 6, d = n & 63;
                if (y == 0) {
                    q_[((size_t)(b * 16 + h) * 2048 + s) * 64 + d] = f2bf(v * QSCALE);
                } else if (y == 1) {
                    k_[((size_t)(b * 16 + h) * 2048 + s) * 64 + d] = f2bf(v);
                } else {
                    vT[((size_t)(b * 16 + h) * 64 + d) * 2048 + s] = f2bf(v);
                }
            }
        }
    }
}

// ---------------- output projection GEMM (128x64, dbuf, proven) ----------------
__device__ __forceinline__ void gemm_kloop(
        const short* __restrict__ Abase, const short* __restrict__ Wbase,
        short* aSb, short* bSb, f32x4 (&acc)[4][2], int w, int lane) {
    const int lr = lane >> 3;
    const int lcs = ((lane & 7) ^ lr) * 8;
    const int l15 = lane & 15, lq = lane >> 4;
    const int wr = w >> 1, wc = w & 1;
    const int cA0 = ((0 + lq) ^ (l15 & 7)) * 8;
    const int cA1 = ((4 + lq) ^ (l15 & 7)) * 8;

#pragma unroll
    for (int j = 0; j < 4; ++j) {
        int r0 = w * 32 + j * 8;
        GLOAD16(&Abase[(size_t)(r0 + lr) * 1024 + lcs], &aSb[r0 * 64]);
    }
#pragma unroll
    for (int j = 0; j < 2; ++j) {
        int r0 = w * 16 + j * 8;
        GLOAD16(&Wbase[(size_t)(r0 + lr) * 1024 + lcs], &bSb[r0 * 64]);
    }

    for (int t = 0; t < 16; ++t) {
        const int cur = t & 1;
        if (t < 15) {
            const int k0 = (t + 1) * 64;
            const int nb = cur ^ 1;
#pragma unroll
            for (int j = 0; j < 4; ++j) {
                int r0 = w * 32 + j * 8;
                GLOAD16(&Abase[(size_t)(r0 + lr) * 1024 + k0 + lcs], &aSb[nb * 8192 + r0 * 64]);
            }
#pragma unroll
            for (int j = 0; j < 2; ++j) {
                int r0 = w * 16 + j * 8;
                GLOAD16(&Wbase[(size_t)(r0 + lr) * 1024 + k0 + lcs], &bSb[nb * 4096 + r0 * 64]);
            }
            asm volatile("s_waitcnt vmcnt(6)" ::: "memory");
        } else {
            asm volatile("s_waitcnt vmcnt(0)" ::: "memory");
        }
        __builtin_amdgcn_s_barrier();
        __builtin_amdgcn_sched_barrier(0);
#pragma unroll
        for (int kf = 0; kf < 2; ++kf) {
            const int ck = kf ? cA1 : cA0;
            short8 af[4], bfr[2];
#pragma unroll
            for (int mi = 0; mi < 4; ++mi)
                af[mi] = *reinterpret_cast<const short8*>(
                    &aSb[cur * 8192 + (wr * 64 + mi * 16 + l15) * 64 + ck]);
#pragma unroll
            for (int ni = 0; ni < 2; ++ni)
                bfr[ni] = *reinterpret_cast<const short8*>(
                    &bSb[cur * 4096 + (wc * 32 + ni * 16 + l15) * 64 + ck]);
#pragma unroll
            for (int mi = 0; mi < 4; ++mi)
#pragma unroll
                for (int ni = 0; ni < 2; ++ni)
                    acc[mi][ni] = __builtin_amdgcn_mfma_f32_16x16x32_bf16(
                        af[mi], bfr[ni], acc[mi][ni], 0, 0, 0);
        }
        asm volatile("s_waitcnt lgkmcnt(0)" ::: "memory");
        __builtin_amdgcn_sched_barrier(0);
        __builtin_amdgcn_s_barrier();
    }
}

__global__ __launch_bounds__(256, 3) void gemm_o(
        const short* __restrict__ A, const short* __restrict__ W,
        const float* __restrict__ bias, float* __restrict__ out) {
    __shared__ __align__(16) short aSb[2 * 128 * 64];
    __shared__ __align__(16) short bSb[2 * 64 * 64];
    const int tid = threadIdx.x;
    const int lane = tid & 63;
    const int w = tid >> 6;
    const int wg = (blockIdx.x & 7) * 64 + (blockIdx.x >> 3);
    const int bn = wg & 15;
    const int bm = wg >> 4;
    const int l15 = lane & 15, lq = lane >> 4;
    const int wr = w >> 1, wc = w & 1;

    f32x4 acc[4][2] = {};
    gemm_kloop(&A[(size_t)(bm * 128) * 1024], &W[(size_t)(bn * 64) * 1024],
               aSb, bSb, acc, w, lane);

#pragma unroll
    for (int mi = 0; mi < 4; ++mi)
#pragma unroll
        for (int ni = 0; ni < 2; ++ni)
#pragma unroll
            for (int i = 0; i < 4; ++i) {
                int m = bm * 128 + wr * 64 + mi * 16 + lq * 4 + i;
                int n = bn * 64 + wc * 32 + ni * 16 + l15;
                out[(size_t)m * 1024 + n] = acc[mi][ni][i] + bias[n];
            }
}

// ---------------- causal flash attention, swapped-QK^T ----------------
// grid = 1024 (32 bh x 32 qtiles, heavy-first), 256 threads = 4 waves x 16 q-rows.
// Swapped QK^T: s = mfma(K_frag, Q_frag) -> lane owns q=lane&15, 16 k-values local.
// Scores in log2 domain (q pre-scaled by 0.125*log2e). Defer-max THR=8.
// P packed to bf16 via v_cvt_pk_bf16_f32, per-wave LDS relayout for PV A-operand.
__global__ __launch_bounds__(256, 4) void attn_fwd(
        const short* __restrict__ qh, const short* __restrict__ kh,
        const short* __restrict__ vT, short* __restrict__ attn) {
    __shared__ __align__(16) short kS[64 * 72];
    __shared__ __align__(16) short vS[64 * 72];
    __shared__ __align__(16) int pS[4][16 * 36];   // [wave][q-row][32 dwords P + 4 pad]
    const int tid = threadIdx.x;
    const int lane = tid & 63;
    const int w = tid >> 6;
    const int l15 = lane & 15, lq = lane >> 4;
    const int bh = blockIdx.x & 31;
    const int qt = 31 - (blockIdx.x >> 5);     // heavy-first
    const int b = bh >> 4, h = bh & 15;
    const size_t head = (size_t)bh * 2048 * 64;
    const short* qp = qh + head;
    const short* kp = kh + head;
    const short* vp = vT + head;
    const int qw0 = qt * 64 + w * 16;          // wave's first q row

    short8 qf_[2];
#pragma unroll
    for (int kf = 0; kf < 2; ++kf)
        qf_[kf] = *reinterpret_cast<const short8*>(
            &qp[(size_t)(qw0 + l15) * 64 + kf * 32 + lq * 8]);

    f32x4 o[4] = {};
    float m_ = -1e30f, l_ = 0.f;

    // staging: 256 threads, each owns 2 short8 pieces of K and of V per tile
    const int sr = tid >> 3;            // 0..31
    const int sc = (tid & 7) * 8;       // shorts

    const int nt = qt + 1;
    short8 kra = *reinterpret_cast<const short8*>(&kp[(size_t)sr * 64 + sc]);
    short8 krb = *reinterpret_cast<const short8*>(&kp[(size_t)(sr + 32) * 64 + sc]);
    short8 vra = *reinterpret_cast<const short8*>(&vp[(size_t)sr * 2048 + sc]);
    short8 vrb = *reinterpret_cast<const short8*>(&vp[(size_t)(sr + 32) * 2048 + sc]);
    *reinterpret_cast<short8*>(&kS[sr * 72 + sc]) = kra;
    *reinterpret_cast<short8*>(&kS[(sr + 32) * 72 + sc]) = krb;
    *reinterpret_cast<short8*>(&vS[sr * 72 + sc]) = vra;
    *reinterpret_cast<short8*>(&vS[(sr + 32) * 72 + sc]) = vrb;
    __syncthreads();

    for (int t = 0; t < nt; ++t) {
        if (t + 1 < nt) {  // issue-early next tile
            kra = *reinterpret_cast<const short8*>(
                &kp[(size_t)((t + 1) * 64 + sr) * 64 + sc]);
            krb = *reinterpret_cast<const short8*>(
                &kp[(size_t)((t + 1) * 64 + sr + 32) * 64 + sc]);
            vra = *reinterpret_cast<const short8*>(
                &vp[(size_t)sr * 2048 + (t + 1) * 64 + sc]);
            vrb = *reinterpret_cast<const short8*>(
                &vp[(size_t)(sr + 32) * 2048 + (t + 1) * 64 + sc]);
        }
        // ---- QK^T (swapped): s[cf][i] = S[k = t*64+cf*16+lq*4+i, q = qw0+l15]
        f32x4 s[4] = {};
#pragma unroll
        for (int kf = 0; kf < 2; ++kf) {
            short8 kfr[4];
#pragma unroll
            for (int cf = 0; cf < 4; ++cf)
                kfr[cf] = *reinterpret_cast<const short8*>(
                    &kS[(cf * 16 + l15) * 72 + kf * 32 + lq * 8]);
#pragma unroll
            for (int cf = 0; cf < 4; ++cf)
                s[cf] = __builtin_amdgcn_mfma_f32_16x16x32_bf16(
                    kfr[cf], qf_[kf], s[cf], 0, 0, 0);
        }
        if (t == qt) {  // diagonal tile: causal mask (k > q)
            const int q = qw0 + l15;
#pragma unroll
            for (int cf = 0; cf < 4; ++cf)
#pragma unroll
                for (int i = 0; i < 4; ++i)
                    if (t * 64 + cf * 16 + lq * 4 + i > q) s[cf][i] = -1e30f;
        }
        // ---- row max (in-lane tree + 2 shuffles)
        float pmax = fmaxf(fmaxf(fmaxf(s[0][0], s[0][1]), fmaxf(s[0][2], s[0][3])),
                           fmaxf(fmaxf(s[1][0], s[1][1]), fmaxf(s[1][2], s[1][3])));
        pmax = fmaxf(pmax, fmaxf(fmaxf(fmaxf(s[2][0], s[2][1]), fmaxf(s[2][2], s[2][3])),
                                 fmaxf(fmaxf(s[3][0], s[3][1]), fmaxf(s[3][2], s[3][3]))));
        pmax = fmaxf(pmax, __shfl_xor(pmax, 16));
        pmax = fmaxf(pmax, __shfl_xor(pmax, 32));
        // ---- defer-max rescale (log2 domain, THR=8 -> P <= 256)
        if (!__all(pmax - m_ <= 8.0f)) {
            float mnew = fmaxf(m_, pmax);
            float scl = exp2fast(m_ - mnew);
            m_ = mnew;
            l_ *= scl;
            float s0 = __shfl(scl, lq * 4 + 0);
            float s1 = __shfl(scl, lq * 4 + 1);
            float s2 = __shfl(scl, lq * 4 + 2);
            float s3 = __shfl(scl, lq * 4 + 3);
#pragma unroll
            for (int df = 0; df < 4; ++df) {
                o[df][0] *= s0; o[df][1] *= s1; o[df][2] *= s2; o[df][3] *= s3;
            }
        }
        // ---- P = exp2(s - m), pack to bf16 pairs, write to pS
        float rsum = 0.f;
#pragma unroll
        for (int cf = 0; cf < 4; ++cf) {
            float p0 = exp2fast(s[cf][0] - m_);
            float p1 = exp2fast(s[cf][1] - m_);
            float p2 = exp2fast(s[cf][2] - m_);
            float p3 = exp2fast(s[cf][3] - m_);
            rsum += (p0 + p1) + (p2 + p3);
            pS[w][l15 * 36 + cf * 8 + lq * 2 + 0] = cvt_pk_bf16(p0, p1);
            pS[w][l15 * 36 + cf * 8 + lq * 2 + 1] = cvt_pk_bf16(p2, p3);
        }
        rsum += __shfl_xor(rsum, 16);
        rsum += __shfl_xor(rsum, 32);
        l_ += rsum;
        asm volatile("s_waitcnt lgkmcnt(0)" ::: "memory");
        __builtin_amdgcn_sched_barrier(0);
        // ---- PV: o[q, d] += P[q, kk] * V^T[d, kk]
#pragma unroll
        for (int kk = 0; kk < 2; ++kk) {
            short8 pa = *reinterpret_cast<const short8*>(
                &pS[w][l15 * 36 + kk * 16 + lq * 4]);
            short8 vb[4];
#pragma unroll
            for (int df = 0; df < 4; ++df)
                vb[df] = *reinterpret_cast<const short8*>(
                    &vS[(df * 16 + l15) * 72 + kk * 32 + lq * 8]);
#pragma unroll
            for (int df = 0; df < 4; ++df)
                o[df] = __builtin_amdgcn_mfma_f32_16x16x32_bf16(
                    pa, vb[df], o[df], 0, 0, 0);
        }
        __syncthreads();   // all reads of kS/vS done
        if (t + 1 < nt) {  // write-late next tile
            *reinterpret_cast<short8*>(&kS[sr * 72 + sc]) = kra;
            *reinterpret_cast<short8*>(&kS[(sr + 32) * 72 + sc]) = krb;
            *reinterpret_cast<short8*>(&vS[sr * 72 + sc]) = vra;
            *reinterpret_cast<short8*>(&vS[(sr + 32) * 72 + sc]) = vrb;
        }
        __syncthreads();
    }

    // epilogue: o rows are q = qw0 + lq*4 + i; l_ lives at lane l15=q-local
#pragma unroll
    for (int i = 0; i < 4; ++i) {
        float li = __shfl(l_, lq * 4 + i);
        float rinv = 1.0f / li;
        int sg = qw0 + lq * 4 + i;
        size_t mrow = (size_t)b * 2048 + sg;
#pragma unroll
        for (int df = 0; df < 4; ++df) {
            int col = h * 64 + df * 16 + l15;
            attn[mrow * 1024 + col] = f2bf(o[df][i] * rinv);
        }
    }
}

extern "C" void kernel_launch(void* const* d_in, const int* in_sizes, int n_in,
                              void* d_out, int out_size, void* d_ws, size_t ws_size,
                              hipStream_t stream) {
    const float* Q  = (const float*)d_in[0];
    const float* K  = (const float*)d_in[1];
    const float* V  = (const float*)d_in[2];
    // d_in[3] = causal mask, applied analytically
    const float* Wq = (const float*)d_in[4];
    const float* bq = (const float*)d_in[5];
    const float* Wk = (const float*)d_in[6];
    const float* bk = (const float*)d_in[7];
    const float* Wv = (const float*)d_in[8];
    const float* bv = (const float*)d_in[9];
    const float* Wo = (const float*)d_in[10];
    const float* bo = (const float*)d_in[11];

    char* ws = (char*)d_ws;
    short* Qb   = (short*)(ws);
    short* Kb   = (short*)(ws + 8388608);
    short* Vb   = (short*)(ws + 16777216);
    short* Wqb  = (short*)(ws + 25165824);
    short* Wkb  = (short*)(ws + 27262976);
    short* Wvb  = (short*)(ws + 29360128);
    short* Wob  = (short*)(ws + 31457280);
    short* q_   = (short*)(ws + 33554432);
    short* k_   = (short*)(ws + 41943040);
    short* vT   = (short*)(ws + 50331648);
    short* attn = Qb;  // Qb dead after gemm_qkv; reuse for attention output

    dim3 cb(256);
    convert_qkv<<<dim3(1024, 3), cb, 0, stream>>>(Q, K, V, Qb, Kb, Vb, 4194304 / 4);
    convert_w<<<dim3(512, 4), cb, 0, stream>>>(Wq, Wk, Wv, Wo, Wqb, Wkb, Wvb, Wob, 1048576 / 4);

    gemm_qkv<<<dim3(256, 3), cb, 0, stream>>>(Qb, Kb, Vb, Wqb, Wkb, Wvb,
                                              bq, bk, bv, q_, k_, vT);

    attn_fwd<<<dim3(1024), cb, 0, stream>>>(q_, k_, vT, attn);

    gemm_o<<<dim3(512), cb, 0, stream>>>(attn, Wob, bo, (float*)d_out);
}

// Round 7
// 222.056 us; speedup vs baseline: 1.5688x; 1.0262x over previous
//
#include <hip/hip_runtime.h>
#include <hip/hip_bf16.h>

typedef __attribute__((ext_vector_type(8))) short short8;
typedef __attribute__((ext_vector_type(4))) short short4v;
typedef __attribute__((ext_vector_type(4))) float f32x4;
typedef __attribute__((ext_vector_type(4))) int i32x4;

static __device__ __forceinline__ short f2bf(float f) {
    __hip_bfloat16 h = __float2bfloat16(f);
    return __builtin_bit_cast(short, h);
}

// v_exp_f32 computes 2^x directly (scores pre-scaled by log2e)
static __device__ __forceinline__ float exp2fast(float x) {
    float r;
    asm("v_exp_f32 %0, %1" : "=v"(r) : "v"(x));
    return r;
}

// pack two f32 -> two bf16 in one dword (lo=a, hi=b)
static __device__ __forceinline__ unsigned cvt_pk_bf16(float a, float b) {
    unsigned r;
    asm("v_cvt_pk_bf16_f32 %0, %1, %2" : "=v"(r) : "v"(a), "v"(b));
    return r;
}

#define GLOAD16(g, l) __builtin_amdgcn_global_load_lds( \
    (const __attribute__((address_space(1))) void*)(g), \
    (__attribute__((address_space(3))) void*)(l), 16, 0, 0)

// ---------------- fused fp32 -> bf16 convert (7 arrays, grid.y selects) ----------------
__global__ __launch_bounds__(256) void convert_all(
        const float* __restrict__ q, const float* __restrict__ k, const float* __restrict__ v,
        const float* __restrict__ wq, const float* __restrict__ wk,
        const float* __restrict__ wv, const float* __restrict__ wo,
        short* __restrict__ oq, short* __restrict__ ok, short* __restrict__ ov,
        short* __restrict__ owq, short* __restrict__ owk,
        short* __restrict__ owv, short* __restrict__ owo) {
    const int y = blockIdx.y;
    const float* in;
    short* out;
    int n4;
    switch (y) {
        case 0: in = q;  out = oq;  n4 = 1048576; break;
        case 1: in = k;  out = ok;  n4 = 1048576; break;
        case 2: in = v;  out = ov;  n4 = 1048576; break;
        case 3: in = wq; out = owq; n4 = 262144;  break;
        case 4: in = wk; out = owk; n4 = 262144;  break;
        case 5: in = wv; out = owv; n4 = 262144;  break;
        default: in = wo; out = owo; n4 = 262144; break;
    }
    int i = blockIdx.x * blockDim.x + threadIdx.x;
    int stride = gridDim.x * blockDim.x;
    for (; i < n4; i += stride) {
        f32x4 vv = reinterpret_cast<const f32x4*>(in)[i];
        short4v o;
        o.x = f2bf(vv.x); o.y = f2bf(vv.y); o.z = f2bf(vv.z); o.w = f2bf(vv.w);
        reinterpret_cast<short4v*>(out)[i] = o;
    }
}

// ---------------- fused QKV projection GEMM (m97 structure) ----------------
// 128x128 tile, 4 waves (2x2, 64x64 each, 4x4 acc), BK=64 single-buffered
// gload_lds w/ both-sides XOR swizzle. grid = (256, 3), 3 blocks/CU.
__global__ __launch_bounds__(256, 3) void gemm_qkv(
        const short* __restrict__ Qb, const short* __restrict__ Kb, const short* __restrict__ Vb,
        const short* __restrict__ Wq, const short* __restrict__ Wk, const short* __restrict__ Wv,
        const float* __restrict__ bq, const float* __restrict__ bk, const float* __restrict__ bv,
        short* __restrict__ q_, short* __restrict__ k_, short* __restrict__ vT) {
    __shared__ __align__(16) short aS[128 * 64];
    __shared__ __align__(16) short bS[128 * 64];
    const int tid = threadIdx.x;
    const int lane = tid & 63;
    const int w = tid >> 6;
    const int wr = w >> 1, wc = w & 1;
    const int l15 = lane & 15, lq = lane >> 4;
    const int lr = lane >> 3;
    const int lcs = ((lane & 7) ^ lr) * 8;   // pre-swizzled global col (shorts)
    const int y = blockIdx.y;
    const int wg = (blockIdx.x & 7) * 32 + (blockIdx.x >> 3);  // XCD swizzle (256%8==0)
    const int bn = wg & 7;    // N/128 = 8
    const int bm = wg >> 3;   // M/128 = 32

    const short* A = y == 0 ? Qb : y == 1 ? Kb : Vb;
    const short* W = y == 0 ? Wq : y == 1 ? Wk : Wv;
    const float* bias = y == 0 ? bq : y == 1 ? bk : bv;
    const short* Ab = A + (size_t)(bm * 128) * 1024;
    const short* Wb = W + (size_t)(bn * 128) * 1024;

    f32x4 acc[4][4] = {};

    for (int t = 0; t < 16; ++t) {
        const int k0 = t * 64;
#pragma unroll
        for (int j = 0; j < 4; ++j) {
            int r0 = w * 32 + j * 8;
            GLOAD16(&Ab[(size_t)(r0 + lr) * 1024 + k0 + lcs], &aS[r0 * 64]);
        }
#pragma unroll
        for (int j = 0; j < 4; ++j) {
            int r0 = w * 32 + j * 8;
            GLOAD16(&Wb[(size_t)(r0 + lr) * 1024 + k0 + lcs], &bS[r0 * 64]);
        }
        asm volatile("s_waitcnt vmcnt(0)" ::: "memory");
        __builtin_amdgcn_s_barrier();
#pragma unroll
        for (int kf = 0; kf < 2; ++kf) {
            const int ck = ((kf * 4 + lq) ^ (l15 & 7)) * 8;
            short8 af[4], bfr[4];
#pragma unroll
            for (int mi = 0; mi < 4; ++mi)
                af[mi] = *reinterpret_cast<const short8*>(
                    &aS[(wr * 64 + mi * 16 + l15) * 64 + ck]);
#pragma unroll
            for (int ni = 0; ni < 4; ++ni)
                bfr[ni] = *reinterpret_cast<const short8*>(
                    &bS[(wc * 64 + ni * 16 + l15) * 64 + ck]);
#pragma unroll
            for (int mi = 0; mi < 4; ++mi)
#pragma unroll
                for (int ni = 0; ni < 4; ++ni)
                    acc[mi][ni] = __builtin_amdgcn_mfma_f32_16x16x32_bf16(
                        af[mi], bfr[ni], acc[mi][ni], 0, 0, 0);
        }
        asm volatile("s_waitcnt lgkmcnt(0)" ::: "memory");
        __builtin_amdgcn_sched_barrier(0);
        __builtin_amdgcn_s_barrier();
    }

    // q pre-scaled by 1/sqrt(64) * log2(e) so attention scores are log2-domain
    const float QSCALE = 0.125f * 1.44269504f;
#pragma unroll
    for (int mi = 0; mi < 4; ++mi) {
#pragma unroll
        for (int ni = 0; ni < 4; ++ni) {
#pragma unroll
            for (int i = 0; i < 4; ++i) {
                int m = bm * 128 + wr * 64 + mi * 16 + lq * 4 + i;
                int n = bn * 128 + wc * 64 + ni * 16 + l15;
                float v = acc[mi][ni][i] + bias[n];
                int b = m >> 11, s = m & 2047, h = n >> 6, d = n & 63;
                if (y == 0) {
                    q_[((size_t)(b * 16 + h) * 2048 + s) * 64 + d] = f2bf(v * QSCALE);
                } else if (y == 1) {
                    k_[((size_t)(b * 16 + h) * 2048 + s) * 64 + d] = f2bf(v);
                } else {
                    vT[((size_t)(b * 16 + h) * 64 + d) * 2048 + s] = f2bf(v);
                }
            }
        }
    }
}

// ---------------- output projection GEMM (128x64, dbuf, proven) ----------------
__device__ __forceinline__ void gemm_kloop(
        const short* __restrict__ Abase, const short* __restrict__ Wbase,
        short* aSb, short* bSb, f32x4 (&acc)[4][2], int w, int lane) {
    const int lr = lane >> 3;
    const int lcs = ((lane & 7) ^ lr) * 8;
    const int l15 = lane & 15, lq = lane >> 4;
    const int wr = w >> 1, wc = w & 1;
    const int cA0 = ((0 + lq) ^ (l15 & 7)) * 8;
    const int cA1 = ((4 + lq) ^ (l15 & 7)) * 8;

#pragma unroll
    for (int j = 0; j < 4; ++j) {
        int r0 = w * 32 + j * 8;
        GLOAD16(&Abase[(size_t)(r0 + lr) * 1024 + lcs], &aSb[r0 * 64]);
    }
#pragma unroll
    for (int j = 0; j < 2; ++j) {
        int r0 = w * 16 + j * 8;
        GLOAD16(&Wbase[(size_t)(r0 + lr) * 1024 + lcs], &bSb[r0 * 64]);
    }

    for (int t = 0; t < 16; ++t) {
        const int cur = t & 1;
        if (t < 15) {
            const int k0 = (t + 1) * 64;
            const int nb = cur ^ 1;
#pragma unroll
            for (int j = 0; j < 4; ++j) {
                int r0 = w * 32 + j * 8;
                GLOAD16(&Abase[(size_t)(r0 + lr) * 1024 + k0 + lcs], &aSb[nb * 8192 + r0 * 64]);
            }
#pragma unroll
            for (int j = 0; j < 2; ++j) {
                int r0 = w * 16 + j * 8;
                GLOAD16(&Wbase[(size_t)(r0 + lr) * 1024 + k0 + lcs], &bSb[nb * 4096 + r0 * 64]);
            }
            asm volatile("s_waitcnt vmcnt(6)" ::: "memory");
        } else {
            asm volatile("s_waitcnt vmcnt(0)" ::: "memory");
        }
        __builtin_amdgcn_s_barrier();
        __builtin_amdgcn_sched_barrier(0);
#pragma unroll
        for (int kf = 0; kf < 2; ++kf) {
            const int ck = kf ? cA1 : cA0;
            short8 af[4], bfr[2];
#pragma unroll
            for (int mi = 0; mi < 4; ++mi)
                af[mi] = *reinterpret_cast<const short8*>(
                    &aSb[cur * 8192 + (wr * 64 + mi * 16 + l15) * 64 + ck]);
#pragma unroll
            for (int ni = 0; ni < 2; ++ni)
                bfr[ni] = *reinterpret_cast<const short8*>(
                    &bSb[cur * 4096 + (wc * 32 + ni * 16 + l15) * 64 + ck]);
#pragma unroll
            for (int mi = 0; mi < 4; ++mi)
#pragma unroll
                for (int ni = 0; ni < 2; ++ni)
                    acc[mi][ni] = __builtin_amdgcn_mfma_f32_16x16x32_bf16(
                        af[mi], bfr[ni], acc[mi][ni], 0, 0, 0);
        }
        asm volatile("s_waitcnt lgkmcnt(0)" ::: "memory");
        __builtin_amdgcn_sched_barrier(0);
        __builtin_amdgcn_s_barrier();
    }
}

__global__ __launch_bounds__(256, 3) void gemm_o(
        const short* __restrict__ A, const short* __restrict__ W,
        const float* __restrict__ bias, float* __restrict__ out) {
    __shared__ __align__(16) short aSb[2 * 128 * 64];
    __shared__ __align__(16) short bSb[2 * 64 * 64];
    const int tid = threadIdx.x;
    const int lane = tid & 63;
    const int w = tid >> 6;
    const int wg = (blockIdx.x & 7) * 64 + (blockIdx.x >> 3);
    const int bn = wg & 15;
    const int bm = wg >> 4;
    const int l15 = lane & 15, lq = lane >> 4;
    const int wr = w >> 1, wc = w & 1;

    f32x4 acc[4][2] = {};
    gemm_kloop(&A[(size_t)(bm * 128) * 1024], &W[(size_t)(bn * 64) * 1024],
               aSb, bSb, acc, w, lane);

#pragma unroll
    for (int mi = 0; mi < 4; ++mi)
#pragma unroll
        for (int ni = 0; ni < 2; ++ni)
#pragma unroll
            for (int i = 0; i < 4; ++i) {
                int m = bm * 128 + wr * 64 + mi * 16 + lq * 4 + i;
                int n = bn * 64 + wc * 32 + ni * 16 + l15;
                out[(size_t)m * 1024 + n] = acc[mi][ni][i] + bias[n];
            }
}

// ---------------- causal flash attention, swapped-QK^T ----------------
// grid = 1024 (32 bh x 32 qtiles, heavy-first), 256 threads = 4 waves x 16 q-rows.
// Swapped QK^T: s = mfma(K_frag, Q_frag) -> lane owns q=lane&15, 16 k-values local.
// Scores in log2 domain. Defer-max THR=8. kS/vS XOR-swizzled (chunk ^= row&7).
// P redistributed to PV A-fragment via 4-lane shuffle transpose. NOTE shfl
// semantics: val is evaluated on the SOURCE lane, so both hi-halves are
// shuffled and the destination selects by its own hi (round-6 bugfix).
__global__ __launch_bounds__(256, 4) void attn_fwd(
        const short* __restrict__ qh, const short* __restrict__ kh,
        const short* __restrict__ vT, short* __restrict__ attn) {
    __shared__ __align__(16) short kS[64 * 64];
    __shared__ __align__(16) short vS[64 * 64];
    const int tid = threadIdx.x;
    const int lane = tid & 63;
    const int l15 = lane & 15, lq = lane >> 4;
    const int w = tid >> 6;
    const int hi = (lane >> 5) & 1;            // lq >= 2
    const int bh = blockIdx.x & 31;
    const int qt = 31 - (blockIdx.x >> 5);     // heavy-first
    const int b = bh >> 4, h = bh & 15;
    const size_t head = (size_t)bh * 2048 * 64;
    const short* qp = qh + head;
    const short* kp = kh + head;
    const short* vp = vT + head;
    const int qw0 = qt * 64 + w * 16;          // wave's first q row

    short8 qf_[2];
#pragma unroll
    for (int kf = 0; kf < 2; ++kf)
        qf_[kf] = *reinterpret_cast<const short8*>(
            &qp[(size_t)(qw0 + l15) * 64 + kf * 32 + lq * 8]);

    f32x4 o[4] = {};
    float m_ = -1e30f, l_ = 0.f;

    // staging: thread owns rows sr, sr+32, chunk sc8; XOR-swizzled LDS dest
    const int sr = tid >> 3;                   // 0..31
    const int sc8 = tid & 7;                   // 16B chunk
    const int scg = sc8 * 8;                   // global col (shorts)
    const int sls = sr * 64 + (sc8 ^ (sr & 7)) * 8;          // LDS dest (shorts)
    const int sls2 = (sr + 32) * 64 + (sc8 ^ (sr & 7)) * 8;  // (sr+32)&7 == sr&7

    const int nt = qt + 1;
    short8 kra = *reinterpret_cast<const short8*>(&kp[(size_t)sr * 64 + scg]);
    short8 krb = *reinterpret_cast<const short8*>(&kp[(size_t)(sr + 32) * 64 + scg]);
    short8 vra = *reinterpret_cast<const short8*>(&vp[(size_t)sr * 2048 + scg]);
    short8 vrb = *reinterpret_cast<const short8*>(&vp[(size_t)(sr + 32) * 2048 + scg]);
    *reinterpret_cast<short8*>(&kS[sls]) = kra;
    *reinterpret_cast<short8*>(&kS[sls2]) = krb;
    *reinterpret_cast<short8*>(&vS[sls]) = vra;
    *reinterpret_cast<short8*>(&vS[sls2]) = vrb;
    __syncthreads();

    for (int t = 0; t < nt; ++t) {
        if (t + 1 < nt) {  // issue-early next tile
            kra = *reinterpret_cast<const short8*>(
                &kp[(size_t)((t + 1) * 64 + sr) * 64 + scg]);
            krb = *reinterpret_cast<const short8*>(
                &kp[(size_t)((t + 1) * 64 + sr + 32) * 64 + scg]);
            vra = *reinterpret_cast<const short8*>(
                &vp[(size_t)sr * 2048 + (t + 1) * 64 + scg]);
            vrb = *reinterpret_cast<const short8*>(
                &vp[(size_t)(sr + 32) * 2048 + (t + 1) * 64 + scg]);
        }
        // ---- QK^T (swapped): s[cf][i] = S[k = t*64+cf*16+lq*4+i, q = qw0+l15]
        f32x4 s[4] = {};
#pragma unroll
        for (int kf = 0; kf < 2; ++kf) {
            short8 kfr[4];
#pragma unroll
            for (int cf = 0; cf < 4; ++cf)
                kfr[cf] = *reinterpret_cast<const short8*>(
                    &kS[(cf * 16 + l15) * 64 + ((kf * 4 + lq) ^ (l15 & 7)) * 8]);
#pragma unroll
            for (int cf = 0; cf < 4; ++cf)
                s[cf] = __builtin_amdgcn_mfma_f32_16x16x32_bf16(
                    kfr[cf], qf_[kf], s[cf], 0, 0, 0);
        }
        if (t == qt) {  // diagonal tile: causal mask (k > q)
            const int q = qw0 + l15;
#pragma unroll
            for (int cf = 0; cf < 4; ++cf)
#pragma unroll
                for (int i = 0; i < 4; ++i)
                    if (t * 64 + cf * 16 + lq * 4 + i > q) s[cf][i] = -1e30f;
        }
        // ---- row max (in-lane tree + 2 shuffles across the 4 lanes sharing l15)
        float pmax = fmaxf(fmaxf(fmaxf(s[0][0], s[0][1]), fmaxf(s[0][2], s[0][3])),
                           fmaxf(fmaxf(s[1][0], s[1][1]), fmaxf(s[1][2], s[1][3])));
        pmax = fmaxf(pmax, fmaxf(fmaxf(fmaxf(s[2][0], s[2][1]), fmaxf(s[2][2], s[2][3])),
                                 fmaxf(fmaxf(s[3][0], s[3][1]), fmaxf(s[3][2], s[3][3]))));
        pmax = fmaxf(pmax, __shfl_xor(pmax, 16));
        pmax = fmaxf(pmax, __shfl_xor(pmax, 32));
        // ---- defer-max rescale (log2 domain, THR=8 -> P <= 256)
        if (!__all(pmax - m_ <= 8.0f)) {
            float mnew = fmaxf(m_, pmax);
            float scl = exp2fast(m_ - mnew);
            m_ = mnew;
            l_ *= scl;
            float s0 = __shfl(scl, lq * 4 + 0);
            float s1 = __shfl(scl, lq * 4 + 1);
            float s2 = __shfl(scl, lq * 4 + 2);
            float s3 = __shfl(scl, lq * 4 + 3);
#pragma unroll
            for (int df = 0; df < 4; ++df) {
                o[df][0] *= s0; o[df][1] *= s1; o[df][2] *= s2; o[df][3] *= s3;
            }
        }
        // ---- P = exp2(s - m), pack into 8 dwords (pair p=8cf+2lq+m at g=2cf+m)
        float rsum = 0.f;
        unsigned P8[8];
#pragma unroll
        for (int cf = 0; cf < 4; ++cf) {
            float p0 = exp2fast(s[cf][0] - m_);
            float p1 = exp2fast(s[cf][1] - m_);
            float p2 = exp2fast(s[cf][2] - m_);
            float p3 = exp2fast(s[cf][3] - m_);
            rsum += (p0 + p1) + (p2 + p3);
            P8[2 * cf]     = cvt_pk_bf16(p0, p1);
            P8[2 * cf + 1] = cvt_pk_bf16(p2, p3);
        }
        rsum += __shfl_xor(rsum, 16);
        rsum += __shfl_xor(rsum, 32);
        l_ += rsum;
        // ---- PV: 4-lane shuffle transpose builds A-fragment (no LDS, no barrier)
        // dest lane (l15,lq), dword j needs pair p=16kk+4lq+j, located on source
        // lane l15+16*(2*(lq&1)+(j>>1)) at dword g=4kk+2*hi_dest+(j&1).
        // Shuffle BOTH hi-half candidates (val evaluated on source lane), select
        // by destination's own hi.
#pragma unroll
        for (int kk = 0; kk < 2; ++kk) {
            int dw[4];
#pragma unroll
            for (int j = 0; j < 4; ++j) {
                int src = l15 + 16 * (2 * (lq & 1) + (j >> 1));
                int vlo = __shfl((int)P8[4 * kk + (j & 1)], src);
                int vhi = __shfl((int)P8[4 * kk + 2 + (j & 1)], src);
                dw[j] = hi ? vhi : vlo;
            }
            i32x4 dwv; dwv.x = dw[0]; dwv.y = dw[1]; dwv.z = dw[2]; dwv.w = dw[3];
            short8 pa = __builtin_bit_cast(short8, dwv);
            short8 vb[4];
#pragma unroll
            for (int df = 0; df < 4; ++df)
                vb[df] = *reinterpret_cast<const short8*>(
                    &vS[(df * 16 + l15) * 64 + ((kk * 4 + lq) ^ (l15 & 7)) * 8]);
#pragma unroll
            for (int df = 0; df < 4; ++df)
                o[df] = __builtin_amdgcn_mfma_f32_16x16x32_bf16(
                    pa, vb[df], o[df], 0, 0, 0);
        }
        __syncthreads();   // all reads of kS/vS done
        if (t + 1 < nt) {  // write-late next tile
            *reinterpret_cast<short8*>(&kS[sls]) = kra;
            *reinterpret_cast<short8*>(&kS[sls2]) = krb;
            *reinterpret_cast<short8*>(&vS[sls]) = vra;
            *reinterpret_cast<short8*>(&vS[sls2]) = vrb;
        }
        __syncthreads();
    }

    // epilogue: o rows are q = qw0 + lq*4 + i; l_ lives at lane l15=q-local
#pragma unroll
    for (int i = 0; i < 4; ++i) {
        float li = __shfl(l_, lq * 4 + i);
        float rinv = 1.0f / li;
        int sg = qw0 + lq * 4 + i;
        size_t mrow = (size_t)b * 2048 + sg;
#pragma unroll
        for (int df = 0; df < 4; ++df) {
            int col = h * 64 + df * 16 + l15;
            attn[mrow * 1024 + col] = f2bf(o[df][i] * rinv);
        }
    }
}

extern "C" void kernel_launch(void* const* d_in, const int* in_sizes, int n_in,
                              void* d_out, int out_size, void* d_ws, size_t ws_size,
                              hipStream_t stream) {
    const float* Q  = (const float*)d_in[0];
    const float* K  = (const float*)d_in[1];
    const float* V  = (const float*)d_in[2];
    // d_in[3] = causal mask, applied analytically
    const float* Wq = (const float*)d_in[4];
    const float* bq = (const float*)d_in[5];
    const float* Wk = (const float*)d_in[6];
    const float* bk = (const float*)d_in[7];
    const float* Wv = (const float*)d_in[8];
    const float* bv = (const float*)d_in[9];
    const float* Wo = (const float*)d_in[10];
    const float* bo = (const float*)d_in[11];

    char* ws = (char*)d_ws;
    short* Qb   = (short*)(ws);
    short* Kb   = (short*)(ws + 8388608);
    short* Vb   = (short*)(ws + 16777216);
    short* Wqb  = (short*)(ws + 25165824);
    short* Wkb  = (short*)(ws + 27262976);
    short* Wvb  = (short*)(ws + 29360128);
    short* Wob  = (short*)(ws + 31457280);
    short* q_   = (short*)(ws + 33554432);
    short* k_   = (short*)(ws + 41943040);
    short* vT   = (short*)(ws + 50331648);
    short* attn = Qb;  // Qb dead after gemm_qkv; reuse for attention output

    dim3 cb(256);
    convert_all<<<dim3(512, 7), cb, 0, stream>>>(Q, K, V, Wq, Wk, Wv, Wo,
                                                 Qb, Kb, Vb, Wqb, Wkb, Wvb, Wob);

    gemm_qkv<<<dim3(256, 3), cb, 0, stream>>>(Qb, Kb, Vb, Wqb, Wkb, Wvb,
                                              bq, bk, bv, q_, k_, vT);

    attn_fwd<<<dim3(1024), cb, 0, stream>>>(q_, k_, vT, attn);

    gemm_o<<<dim3(512), cb, 0, stream>>>(attn, Wob, bo, (float*)d_out);
}